// Round 5
// baseline (781.272 us; speedup 1.0000x reference)
//
#include <hip/hip_runtime.h>

// ScaledDotProductAttention: B=2,H=16,S=2048,DK=DV=64, fp32 in/out, mask (True => -1e9).
// R12 = R9/R10/R11 resubmission (none ran: broker timeouts x4). LDS-free main loop:
//   - Waves = (q-half 32q) x (key-half 32k); K/V/mask fragments wave-private, read
//     directly from global (L2-resident via XCD-aware block swizzle: 4 bh per XCD
//     = 2 MiB < 4 MiB L2).
//   - Score MFMAs use permuted K-row order (hrow = 8*(m>>2) + 4*kt + (m&3)) so the
//     score C-layout is exactly the lane-local A-fragment of the K=32 PV MFMA ->
//     P never round-trips through LDS.
//   - No barriers/glds/pst in the main loop; one epilogue barrier to reduce the two
//     key-halves (O partials + L) through 17 KiB LDS.
//   Rationale: R1 counters showed dur_us = ~668us fixed poison-fills + ~90us kernels;
//   the old kernel's controllable part was LDS-read-bound (~46us of ds_read_b128/CU).

#define LOG2E 1.4426950408889634f
#define QSCALE (0.125f * LOG2E)          // fold 1/sqrt(64) and log2(e) into Q

typedef __attribute__((ext_vector_type(8))) short short8;   // 8 x bf16
typedef __attribute__((ext_vector_type(4))) short short4v;  // 4 x bf16
typedef __attribute__((ext_vector_type(4))) float f32x4;    // MFMA acc
typedef unsigned __attribute__((ext_vector_type(4))) uintv4;

constexpr int S = 2048, D = 64;

__device__ __forceinline__ short bf16rne(float x) {
  union { float f; unsigned u; } cv; cv.f = x;
  unsigned u = cv.u;
  u += 0x7fffu + ((u >> 16) & 1u);
  return (short)(u >> 16);
}

// Merged prep: blocks [0,2048) convert K fp32->bf16; [2048,3072) build bf16 V^T.
// Block 0 wave 0 additionally detects mask format: 1 = byte-packed, 0 = 4-byte elems.
__global__ void prep(const float* __restrict__ kp, const float* __restrict__ vp,
                     short* __restrict__ kb, short* __restrict__ vt,
                     const unsigned* __restrict__ m, int* __restrict__ flag) {
  const int b = blockIdx.x;
  const int tid = threadIdx.x;
  if (b == 0 && tid < 64) {
    unsigned v = m[tid];
    unsigned long long big = __ballot(v > 1u && v != 0x3F800000u);
    unsigned long long isf = __ballot(v == 0x3F800000u);
    if (tid == 0) *flag = (big != 0ull && isf == 0ull) ? 1 : 0;
  }
  if (b < 2048) {
    size_t i = ((size_t)b * 256 + tid) * 8;
    float4 a = *(const float4*)(kp + i);
    float4 c = *(const float4*)(kp + i + 4);
    short8 s;
    s[0] = bf16rne(a.x); s[1] = bf16rne(a.y); s[2] = bf16rne(a.z); s[3] = bf16rne(a.w);
    s[4] = bf16rne(c.x); s[5] = bf16rne(c.y); s[6] = bf16rne(c.z); s[7] = bf16rne(c.w);
    *(short8*)&kb[i] = s;
  } else {
    __shared__ float tile[64][65];
    const int bb = b - 2048;
    const int bh = bb >> 5, k0 = (bb & 31) * 64;
    const float* src = vp + ((size_t)(bh * S + k0)) * D;
#pragma unroll
    for (int i = 0; i < 4; ++i) {
      int row = i * 16 + (tid >> 4);
      int col = (tid & 15) * 4;
      float4 x = *(const float4*)(src + row * D + col);
      tile[row][col] = x.x; tile[row][col + 1] = x.y;
      tile[row][col + 2] = x.z; tile[row][col + 3] = x.w;
    }
    __syncthreads();
#pragma unroll
    for (int i = 0; i < 4; ++i) {
      int dim = i * 16 + (tid >> 4);
      int kb4 = (tid & 15) * 4;
      short4v s;
#pragma unroll
      for (int j = 0; j < 4; ++j) s[j] = bf16rne(tile[kb4 + j][dim]);
      *(short4v*)&vt[((size_t)(bh * D + dim)) * S + k0 + kb4] = s;
    }
  }
}

__launch_bounds__(256, 4)
__global__ void attn_fwd(const float* __restrict__ qp, const short* __restrict__ kb,
                         const short* __restrict__ vt, const void* __restrict__ mp,
                         float* __restrict__ op, const int* __restrict__ fmtp) {
  const int fmt  = *fmtp;
  const int tid  = threadIdx.x;
  const int lane = tid & 63;
  const int w    = tid >> 6;          // wave 0..3
  const int c    = lane & 15;
  const int quad = lane >> 4;
  const int kh   = w & 1;             // key-half (32 keys per iter)
  const int qh   = w >> 1;            // q-half   (32 q-rows)

  // XCD-aware swizzle: 1024 blocks, 8 XCDs; dispatch-consecutive blocks on one XCD
  // cover 128 consecutive logical tiles = 4 bh -> K/V working set 2 MiB < 4 MiB L2.
  const int bid = (blockIdx.x & 7) * 128 + (blockIdx.x >> 3);
  const int bh  = bid >> 5;
  const int q0  = (bid & 31) * 64;

  __shared__ float Olds[2][32][66];   // key-half-1 partial O, padded stride
  __shared__ float Llds[2][32];       // key-half-1 partial L

  // ---- Q B-fragments: qB[qg][kk], lane holds Q[q0+qh*32+qg*16+c][kk*32+quad*8 ..+7]
  short8 qB[2][2];
#pragma unroll
  for (int qg = 0; qg < 2; ++qg) {
    const float* qg_p = qp + ((size_t)(bh * S + q0 + qh * 32 + qg * 16 + c)) * D;
#pragma unroll
    for (int kk = 0; kk < 2; ++kk) {
      const float* p = qg_p + kk * 32 + quad * 8;
      float4 x = *(const float4*)(p);
      float4 y = *(const float4*)(p + 4);
      short8 f;
      f[0] = bf16rne(x.x * QSCALE); f[1] = bf16rne(x.y * QSCALE);
      f[2] = bf16rne(x.z * QSCALE); f[3] = bf16rne(x.w * QSCALE);
      f[4] = bf16rne(y.x * QSCALE); f[5] = bf16rne(y.y * QSCALE);
      f[6] = bf16rne(y.z * QSCALE); f[7] = bf16rne(y.w * QSCALE);
      qB[qg][kk] = f;
    }
  }

  f32x4 O[2][4];
#pragma unroll
  for (int qg = 0; qg < 2; ++qg)
#pragma unroll
    for (int dt = 0; dt < 4; ++dt) O[qg][dt] = (f32x4){0.f, 0.f, 0.f, 0.f};
  float Lp[2] = {0.f, 0.f};

  const short* kbase = kb + ((size_t)(bh * S)) * D;
  const short* vbase = vt + ((size_t)(bh * D)) * S;
  // Permuted K-row order: A-row m of score-MFMA kt holds key 8*(m>>2)+4*kt+(m&3),
  // so C-row (quad*4+r) of MFMA kt is key 8*quad+4*kt+r  => lane-local keys are
  // exactly {8*quad .. 8*quad+7}, i.e. the K=32 PV A-fragment (j = 4*kt+r).
  const int hr0 = 8 * (c >> 2) + (c & 3);

  const size_t mro0 = ((size_t)(bh * S + q0 + qh * 32 + c)) * S;  // qg = 0 row
  const size_t mro1 = mro0 + (size_t)16 * S;                      // qg = 1 row

#pragma unroll 1
  for (int it = 0; it < 32; ++it) {
    const int kO = it * 64 + kh * 32;   // this wave's 32-key window

    // ---- wave-private K fragments (direct from L2, permuted rows) ----
    short8 kf[2][2];
#pragma unroll
    for (int kt = 0; kt < 2; ++kt)
#pragma unroll
      for (int kk = 0; kk < 2; ++kk)
        kf[kt][kk] = *(const short8*)(kbase +
            (size_t)(kO + hr0 + 4 * kt) * 64 + kk * 32 + quad * 8);

    // ---- wave-private V^T B-fragments: V^T[dt*16+c][kO+8*quad .. +7] ----
    short8 vf[4];
#pragma unroll
    for (int dt = 0; dt < 4; ++dt)
      vf[dt] = *(const short8*)(vbase + (size_t)(dt * 16 + c) * S + kO + quad * 8);

    // ---- mask: 8 bytes per qg, byte j <-> key kO+8*quad+j  (j = 4*kt+r) ----
    unsigned long long mbq0, mbq1;
    if (fmt == 1) {
      mbq0 = *(const unsigned long long*)((const unsigned char*)mp + mro0 + kO + 8 * quad);
      mbq1 = *(const unsigned long long*)((const unsigned char*)mp + mro1 + kO + 8 * quad);
    } else {
      const unsigned* m0 = (const unsigned*)mp + mro0 + kO + 8 * quad;
      const unsigned* m1 = (const unsigned*)mp + mro1 + kO + 8 * quad;
      uintv4 a0 = *(const uintv4*)m0, b0 = *(const uintv4*)(m0 + 4);
      uintv4 a1 = *(const uintv4*)m1, b1 = *(const uintv4*)(m1 + 4);
      mbq0 = 0ull; mbq1 = 0ull;
#pragma unroll
      for (int j = 0; j < 4; ++j) {
        if (a0[j]) mbq0 |= 0xffull << (8 * j);
        if (b0[j]) mbq0 |= 0xffull << (8 * (j + 4));
        if (a1[j]) mbq1 |= 0xffull << (8 * j);
        if (b1[j]) mbq1 |= 0xffull << (8 * (j + 4));
      }
    }

#pragma unroll
    for (int qg = 0; qg < 2; ++qg) {
      const unsigned long long mbq = qg ? mbq1 : mbq0;
      // ---- scores: z(kt)[r] = S^T[key=kO+8q+4kt+r][q=qg*16+c] ----
      f32x4 z0 = (f32x4){0.f, 0.f, 0.f, 0.f};
      f32x4 z1 = (f32x4){0.f, 0.f, 0.f, 0.f};
      z0 = __builtin_amdgcn_mfma_f32_16x16x32_bf16(kf[0][0], qB[qg][0], z0, 0, 0, 0);
      z0 = __builtin_amdgcn_mfma_f32_16x16x32_bf16(kf[0][1], qB[qg][1], z0, 0, 0, 0);
      z1 = __builtin_amdgcn_mfma_f32_16x16x32_bf16(kf[1][0], qB[qg][0], z1, 0, 0, 0);
      z1 = __builtin_amdgcn_mfma_f32_16x16x32_bf16(kf[1][1], qB[qg][1], z1, 0, 0, 0);

      // ---- exp + mask + pack: pf[j] = P[q][kO+8*quad+j], lane-local ----
      short8 pf;
      float part = 0.f;
#pragma unroll
      for (int j = 0; j < 8; ++j) {
        float zv = (j < 4) ? z0[j & 3] : z1[j & 3];
        float e = ((mbq >> (8 * j)) & 0xffull) ? 0.f : exp2f(zv);
        part += e;
        pf[j] = bf16rne(e);
      }
      Lp[qg] += part;

      // ---- O += P*V over this 32-key window (A=pf register-direct) ----
#pragma unroll
      for (int dt = 0; dt < 4; ++dt)
        O[qg][dt] = __builtin_amdgcn_mfma_f32_16x16x32_bf16(pf, vf[dt], O[qg][dt], 0, 0, 0);
    }
  }

  // ---- epilogue: reduce the two key-halves ----
  float Lq[2];
#pragma unroll
  for (int qg = 0; qg < 2; ++qg) {
    float t = Lp[qg];
    t += __shfl_xor(t, 16);
    t += __shfl_xor(t, 32);
    Lq[qg] = t;                       // all lanes: full 32-key-window sum for q=qg*16+c
  }

  if (kh == 1) {
#pragma unroll
    for (int qg = 0; qg < 2; ++qg)
#pragma unroll
      for (int dt = 0; dt < 4; ++dt)
#pragma unroll
        for (int r = 0; r < 4; ++r)
          Olds[qh][qg * 16 + quad * 4 + r][dt * 16 + c] = O[qg][dt][r];
    if (quad == 0) {
      Llds[qh][c]      = Lq[0];
      Llds[qh][16 + c] = Lq[1];
    }
  }
  __syncthreads();
  if (kh == 0) {
#pragma unroll
    for (int qg = 0; qg < 2; ++qg)
#pragma unroll
      for (int r = 0; r < 4; ++r) {
        float Ls = __shfl(Lq[qg], (lane & 48) | (quad * 4 + r)) +
                   Llds[qh][qg * 16 + quad * 4 + r];
        float inv = 1.f / Ls;
        const size_t ob =
            ((size_t)(bh * S + q0 + qh * 32 + qg * 16 + quad * 4 + r)) * D;
#pragma unroll
        for (int dt = 0; dt < 4; ++dt)
          op[ob + dt * 16 + c] =
              (O[qg][dt][r] + Olds[qh][qg * 16 + quad * 4 + r][dt * 16 + c]) * inv;
      }
  }
}

extern "C" void kernel_launch(void* const* d_in, const int* in_sizes, int n_in,
                              void* d_out, int out_size, void* d_ws, size_t ws_size,
                              hipStream_t stream) {
  const float* q = (const float*)d_in[0];
  const float* k = (const float*)d_in[1];
  const float* v = (const float*)d_in[2];
  const void*  m = d_in[3];

  short* kbuf = (short*)d_ws;                         // 8 MiB bf16 K
  short* vtb  = (short*)((char*)d_ws + (8u << 20));   // 8 MiB bf16 V^T
  int* flag   = (int*)((char*)d_ws + (16u << 20));

  prep<<<3072, 256, 0, stream>>>(k, v, kbuf, vtb, (const unsigned*)m, flag);
  attn_fwd<<<1024, 256, 0, stream>>>(q, kbuf, vtb, m, (float*)d_out, flag);
}

// Round 6
// 775.712 us; speedup vs baseline: 1.0072x; 1.0072x over previous
//
#include <hip/hip_runtime.h>

// ScaledDotProductAttention: B=2,H=16,S=2048,DK=DV=64, fp32 in/out, mask (True => -1e9).
// R13 = R8 (glds-staged LDS tiles, single barrier/iter, dbuf — measured family 748-758us)
//     + 32q-per-wave blocks (128q, grid 512): K/V tile reads amortized over 2x q-rows
//       -> per-(q,key) LDS reads drop 2.25x (R8: 18 reads/16q-iter; here 16 reads/32q-iter)
//     + R12's HW-VERIFIED permuted-K-row trick (score C-layout == lane-local PV
//       A-fragment) -> P never touches LDS (pst deleted, -2 reads -1 store/iter).
//   Post-mortem R12: fully LDS-free was SLOWER (125us vs 88us kernel budget) — scattered
//   64-line VMEM ops + unprefetched L2 latency beat the LDS path. LDS staging stays;
//   this round reduces how much each wave reads from it per unit of work.

#define LOG2E 1.4426950408889634f
#define QSCALE (0.125f * LOG2E)          // fold 1/sqrt(64) and log2(e) into Q

typedef __attribute__((ext_vector_type(8))) short short8;   // 8 x bf16
typedef __attribute__((ext_vector_type(4))) short short4v;  // 4 x bf16
typedef __attribute__((ext_vector_type(4))) float f32x4;    // MFMA acc
typedef unsigned __attribute__((ext_vector_type(4))) uintv4;

constexpr int S = 2048, D = 64;

__device__ __forceinline__ short bf16rne(float x) {
  union { float f; unsigned u; } cv; cv.f = x;
  unsigned u = cv.u;
  u += 0x7fffu + ((u >> 16) & 1u);
  return (short)(u >> 16);
}

__device__ __forceinline__ void glds16(const void* g, void* l) {
  __builtin_amdgcn_global_load_lds(
      (const __attribute__((address_space(1))) void*)g,
      (__attribute__((address_space(3))) void*)l, 16, 0, 0);
}

// Merged prep: blocks [0,2048) convert K fp32->bf16; [2048,3072) build bf16 V^T.
// Block 0 wave 0 additionally detects mask format: 1 = byte-packed, 0 = 4-byte elems.
__global__ void prep(const float* __restrict__ kp, const float* __restrict__ vp,
                     short* __restrict__ kb, short* __restrict__ vt,
                     const unsigned* __restrict__ m, int* __restrict__ flag) {
  const int b = blockIdx.x;
  const int tid = threadIdx.x;
  if (b == 0 && tid < 64) {
    unsigned v = m[tid];
    unsigned long long big = __ballot(v > 1u && v != 0x3F800000u);
    unsigned long long isf = __ballot(v == 0x3F800000u);
    if (tid == 0) *flag = (big != 0ull && isf == 0ull) ? 1 : 0;
  }
  if (b < 2048) {
    size_t i = ((size_t)b * 256 + tid) * 8;
    float4 a = *(const float4*)(kp + i);
    float4 c = *(const float4*)(kp + i + 4);
    short8 s;
    s[0] = bf16rne(a.x); s[1] = bf16rne(a.y); s[2] = bf16rne(a.z); s[3] = bf16rne(a.w);
    s[4] = bf16rne(c.x); s[5] = bf16rne(c.y); s[6] = bf16rne(c.z); s[7] = bf16rne(c.w);
    *(short8*)&kb[i] = s;
  } else {
    __shared__ float tile[64][65];
    const int bb = b - 2048;
    const int bh = bb >> 5, k0 = (bb & 31) * 64;
    const float* src = vp + ((size_t)(bh * S + k0)) * D;
#pragma unroll
    for (int i = 0; i < 4; ++i) {
      int row = i * 16 + (tid >> 4);
      int col = (tid & 15) * 4;
      float4 x = *(const float4*)(src + row * D + col);
      tile[row][col] = x.x; tile[row][col + 1] = x.y;
      tile[row][col + 2] = x.z; tile[row][col + 3] = x.w;
    }
    __syncthreads();
#pragma unroll
    for (int i = 0; i < 4; ++i) {
      int dim = i * 16 + (tid >> 4);
      int kb4 = (tid & 15) * 4;
      short4v s;
#pragma unroll
      for (int j = 0; j < 4; ++j) s[j] = bf16rne(tile[kb4 + j][dim]);
      *(short4v*)&vt[((size_t)(bh * D + dim)) * S + k0 + kb4] = s;
    }
  }
}

__launch_bounds__(256, 2)
__global__ void attn_fwd(const float* __restrict__ qp, const short* __restrict__ kb,
                         const short* __restrict__ vt, const void* __restrict__ mp,
                         float* __restrict__ op, const int* __restrict__ fmtp) {
  const int fmt  = *fmtp;
  const int tid  = threadIdx.x;
  const int lane = tid & 63;
  const int w    = tid >> 6;          // wave 0..3, owns 32 q-rows
  const int c    = lane & 15;
  const int quad = lane >> 4;

  // XCD-aware swizzle: 512 blocks (512%8==0 -> bijective); one XCD's 64 blocks span
  // 4 bh -> K+V bf16 working set 2 MiB < 4 MiB L2.
  const int bid = (blockIdx.x & 7) * 64 + (blockIdx.x >> 3);
  const int bh  = bid >> 4;
  const int q0  = (bid & 15) * 128;

  __shared__ short ks[2][64 * 64];    // K tile [key][dim], 16B-chunk-xor-swizzled, dbuf
  __shared__ short vs[2][64 * 64];    // V^T tile [dim][key], same swizzle, dbuf

  // ---- Q B-fragments: qB[qg][kk] = Q[q0+w*32+qg*16+c][kk*32+quad*8 ..+7] ----
  short8 qB[2][2];
#pragma unroll
  for (int qg = 0; qg < 2; ++qg) {
    const float* qg_p = qp + ((size_t)(bh * S + q0 + w * 32 + qg * 16 + c)) * D;
#pragma unroll
    for (int kk = 0; kk < 2; ++kk) {
      const float* p = qg_p + kk * 32 + quad * 8;
      float4 x = *(const float4*)(p);
      float4 y = *(const float4*)(p + 4);
      short8 f;
      f[0] = bf16rne(x.x * QSCALE); f[1] = bf16rne(x.y * QSCALE);
      f[2] = bf16rne(x.z * QSCALE); f[3] = bf16rne(x.w * QSCALE);
      f[4] = bf16rne(y.x * QSCALE); f[5] = bf16rne(y.y * QSCALE);
      f[6] = bf16rne(y.z * QSCALE); f[7] = bf16rne(y.w * QSCALE);
      qB[qg][kk] = f;
    }
  }

  f32x4 O[2][4];
#pragma unroll
  for (int qg = 0; qg < 2; ++qg)
#pragma unroll
    for (int dt = 0; dt < 4; ++dt) O[qg][dt] = (f32x4){0.f, 0.f, 0.f, 0.f};
  float Lp[2] = {0.f, 0.f};

  // staging geometry (R8-verified): slot=(h2*4+w)*64+lane; row=(h2*4+w)*8+(lane>>3);
  // LDS chunk position p on row r holds global 16B chunk p^(r&7).
  const int rsub = lane >> 3;
  const int csw  = (lane & 7) ^ rsub;
  const short* kbase = kb + ((size_t)(bh * S)) * D;
  const short* vbase = vt + ((size_t)(bh * D)) * S;

  const size_t mro0 = ((size_t)(bh * S + q0 + w * 32 + c)) * S;  // qg=0 row (elements)
  const size_t mro1 = mro0 + (size_t)16 * S;                     // qg=1 row

  unsigned long long mm[2][2];        // mask prefetch regs [qg][kg]

  auto stage = [&](int it, int buf) {
    const int k0 = it * 64;
#pragma unroll
    for (int h2 = 0; h2 < 2; ++h2) {
      const int row = (h2 * 4 + w) * 8 + rsub;
      glds16(kbase + (size_t)(k0 + row) * 64 + csw * 8,
             (char*)&ks[buf][0] + (h2 * 4 + w) * 1024);
      glds16(vbase + (size_t)row * S + k0 + csw * 8,
             (char*)&vs[buf][0] + (h2 * 4 + w) * 1024);
    }
  };

  auto mload = [&](int it) {
    const int kO = it * 64;
    if (fmt == 1) {
#pragma unroll
      for (int qg = 0; qg < 2; ++qg)
#pragma unroll
        for (int kg = 0; kg < 2; ++kg)
          mm[qg][kg] = __builtin_nontemporal_load((const unsigned long long*)
              ((const unsigned char*)mp + (qg ? mro1 : mro0) + kO + kg * 32 + 8 * quad));
    } else {
#pragma unroll
      for (int qg = 0; qg < 2; ++qg)
#pragma unroll
        for (int kg = 0; kg < 2; ++kg) {
          const unsigned* m0 =
              (const unsigned*)mp + (qg ? mro1 : mro0) + kO + kg * 32 + 8 * quad;
          uintv4 a = __builtin_nontemporal_load((const uintv4*)m0);
          uintv4 b = __builtin_nontemporal_load((const uintv4*)(m0 + 4));
          unsigned long long t = 0ull;
#pragma unroll
          for (int j = 0; j < 4; ++j) {
            if (a[j]) t |= 0xffull << (8 * j);
            if (b[j]) t |= 0xffull << (8 * (j + 4));
          }
          mm[qg][kg] = t;
        }
    }
  };

  // ---- prologue ----
  stage(0, 0);
  mload(0);

  for (int it = 0; it < 32; ++it) {
    const int buf = it & 1;
    // ONE barrier/iter: drains glds(it)+mask(it) (issued a full compute phase ago)
    // and orders prev-iter LDS reads before the writes into buf^1 we issue next.
    __syncthreads();

    if (it + 1 < 32) stage(it + 1, buf ^ 1);

    unsigned long long mb[2][2];
#pragma unroll
    for (int qg = 0; qg < 2; ++qg) {
      mb[qg][0] = mm[qg][0]; mb[qg][1] = mm[qg][1];
    }
    if (it + 1 < 32) mload(it + 1);

#pragma unroll
    for (int kg = 0; kg < 2; ++kg) {
      // ---- K A-fragments, permuted rows: matrix-row m holds key kg*32+8(m>>2)+(m&3)+4kt
      //      -> lane reads LDS row kg*32 + 8*(c>>2) + (c&3) + 4*kt ----
      short8 ka[2][2];
#pragma unroll
      for (int kt = 0; kt < 2; ++kt) {
        const int rr = kg * 32 + 8 * (c >> 2) + (c & 3) + 4 * kt;
        const int r7 = (c & 3) + 4 * kt;          // rr & 7
#pragma unroll
        for (int kk = 0; kk < 2; ++kk)
          ka[kt][kk] = *(const short8*)&ks[buf][rr * 64 + (((kk * 4 + quad) ^ r7) * 8)];
      }
      // ---- V^T B-fragments: V^T[dt*16+c][keys kg*32+quad*8 ..+7] ----
      short8 vb[4];
#pragma unroll
      for (int dt = 0; dt < 4; ++dt)
        vb[dt] = *(const short8*)&vs[buf][(dt * 16 + c) * 64 +
                                          (((kg * 4 + quad) ^ (c & 7)) * 8)];

#pragma unroll
      for (int qg = 0; qg < 2; ++qg) {
        // scores: z(kt)[r] = S^T[key=kg*32+8*quad+4*kt+r][q=qg*16+c]
        f32x4 z0 = (f32x4){0.f, 0.f, 0.f, 0.f};
        f32x4 z1 = (f32x4){0.f, 0.f, 0.f, 0.f};
        z0 = __builtin_amdgcn_mfma_f32_16x16x32_bf16(ka[0][0], qB[qg][0], z0, 0, 0, 0);
        z0 = __builtin_amdgcn_mfma_f32_16x16x32_bf16(ka[0][1], qB[qg][1], z0, 0, 0, 0);
        z1 = __builtin_amdgcn_mfma_f32_16x16x32_bf16(ka[1][0], qB[qg][0], z1, 0, 0, 0);
        z1 = __builtin_amdgcn_mfma_f32_16x16x32_bf16(ka[1][1], qB[qg][1], z1, 0, 0, 0);

        // exp + mask + pack: pf[j=4kt+r] = P[q][kg*32+8*quad+j], lane-local
        short8 pf;
        float part = 0.f;
        const unsigned long long mq = mb[qg][kg];
#pragma unroll
        for (int j = 0; j < 8; ++j) {
          float zv = (j < 4) ? z0[j & 3] : z1[j & 3];
          float e = ((mq >> (8 * j)) & 0xffull) ? 0.f : exp2f(zv);
          part += e;
          pf[j] = bf16rne(e);
        }
        Lp[qg] += part;

        // O += P*V over this 32-key group (A=pf register-direct)
#pragma unroll
        for (int dt = 0; dt < 4; ++dt)
          O[qg][dt] =
              __builtin_amdgcn_mfma_f32_16x16x32_bf16(pf, vb[dt], O[qg][dt], 0, 0, 0);
      }
    }
  }

  // ---- epilogue: wave owns its 32 q-rows completely; no cross-wave reduction ----
#pragma unroll
  for (int qg = 0; qg < 2; ++qg) {
    float t = Lp[qg];
    t += __shfl_xor(t, 16);
    t += __shfl_xor(t, 32);           // all lanes: L for q=qg*16+c
#pragma unroll
    for (int r = 0; r < 4; ++r) {
      float Ls = __shfl(t, (lane & 48) | (quad * 4 + r));
      float inv = 1.f / Ls;
      const size_t ob =
          ((size_t)(bh * S + q0 + w * 32 + qg * 16 + quad * 4 + r)) * D;
#pragma unroll
      for (int dt = 0; dt < 4; ++dt) op[ob + dt * 16 + c] = O[qg][dt][r] * inv;
    }
  }
}

extern "C" void kernel_launch(void* const* d_in, const int* in_sizes, int n_in,
                              void* d_out, int out_size, void* d_ws, size_t ws_size,
                              hipStream_t stream) {
  const float* q = (const float*)d_in[0];
  const float* k = (const float*)d_in[1];
  const float* v = (const float*)d_in[2];
  const void*  m = d_in[3];

  short* kbuf = (short*)d_ws;                         // 8 MiB bf16 K
  short* vtb  = (short*)((char*)d_ws + (8u << 20));   // 8 MiB bf16 V^T
  int* flag   = (int*)((char*)d_ws + (16u << 20));

  prep<<<3072, 256, 0, stream>>>(k, v, kbuf, vtb, (const unsigned*)m, flag);
  attn_fwd<<<512, 256, 0, stream>>>(q, kbuf, vtb, m, (float*)d_out, flag);
}